// Round 1
// baseline (413.314 us; speedup 1.0000x reference)
//
#include <hip/hip_runtime.h>
#include <hip/hip_bf16.h>

#define EMBED 1024
#define HEADS 16
#define HDIM 64
#define FFN 4096
#define SEQ 2048
#define BATCH 2
#define MTOT (BATCH*SEQ)

typedef __attribute__((ext_vector_type(8))) short bf16x8;
typedef __attribute__((ext_vector_type(4))) float f32x4;
typedef unsigned short u16;

__device__ __forceinline__ u16 f2bf(float f) {
  union { float f; unsigned u; } v; v.f = f;
  unsigned r = v.u + 0x7FFFu + ((v.u >> 16) & 1u);
  return (u16)(r >> 16);
}

__device__ __forceinline__ void async_ld16(const void* g, void* l) {
  __builtin_amdgcn_global_load_lds((const __attribute__((address_space(1))) void*)g,
                                   (__attribute__((address_space(3))) void*)l,
                                   16, 0, 0);
}

// ---------------- fp32 -> bf16 convert (vectorized) ----------------
__global__ __launch_bounds__(256) void k_cvt(const float* __restrict__ in,
                                             u16* __restrict__ out, int n4) {
  int i = blockIdx.x * 256 + threadIdx.x;
  int st = gridDim.x * 256;
  for (; i < n4; i += st) {
    float4 v = ((const float4*)in)[i];
    ushort4 o;
    o.x = f2bf(v.x); o.y = f2bf(v.y); o.z = f2bf(v.z); o.w = f2bf(v.w);
    ((ushort4*)out)[i] = o;
  }
}

// ---------------- transpose-convert: w[K,N] fp32 -> wT[N,K] bf16 ----------------
__global__ __launch_bounds__(256) void k_tr(const float* __restrict__ w,
                                            u16* __restrict__ wT, int K, int N) {
  __shared__ u16 tile[32][33];
  int n0 = blockIdx.x * 32, k0 = blockIdx.y * 32;
  int tx = threadIdx.x, ty = threadIdx.y;   // blockDim (32,8)
  #pragma unroll
  for (int i = 0; i < 4; ++i) {
    int k = k0 + ty + i * 8;
    tile[ty + i * 8][tx] = f2bf(w[(size_t)k * N + n0 + tx]);
  }
  __syncthreads();
  #pragma unroll
  for (int i = 0; i < 4; ++i) {
    int n = n0 + ty + i * 8;
    wT[(size_t)n * K + k0 + tx] = tile[tx][ty + i * 8];
  }
}

// ---------------- MFMA GEMM: C[M,N] = A[M,K] @ BT[N,K]^T + bias ----------------
// OMODE: 0 = bf16 out [M,N], 1 = f32 out [M,N], 2 = QKV scatter to [B,H,S,D] bf16
template <int OMODE, bool RELU>
__global__ __launch_bounds__(256) void k_gemm(
    const u16* __restrict__ A, const u16* __restrict__ BT,
    const float* __restrict__ bias,
    void* __restrict__ out0, void* __restrict__ out1, void* __restrict__ out2,
    int M, int N, int K) {
  __shared__ u16 As[128 * 32];
  __shared__ u16 Bs[128 * 32];
  const int tid = threadIdx.x;
  const int lane = tid & 63, g = lane >> 4, li = lane & 15;
  const int wid = tid >> 6, wm = wid >> 1, wn = wid & 1;
  const int m0 = blockIdx.y * 128, n0 = blockIdx.x * 128;

  f32x4 acc[4][4] = {};

  const u16* Ablk = A + (size_t)m0 * K;
  const u16* Bblk = BT + (size_t)n0 * K;
  const int arow = tid >> 2, acol = (tid & 3) * 8;

  for (int kt = 0; kt < K; kt += 32) {
    async_ld16(Ablk + (size_t)arow * K + kt + acol, As + tid * 8);
    async_ld16(Ablk + (size_t)(arow + 64) * K + kt + acol, As + 2048 + tid * 8);
    async_ld16(Bblk + (size_t)arow * K + kt + acol, Bs + tid * 8);
    async_ld16(Bblk + (size_t)(arow + 64) * K + kt + acol, Bs + 2048 + tid * 8);
    __syncthreads();
    bf16x8 af[4], bfr[4];
    #pragma unroll
    for (int i = 0; i < 4; ++i)
      af[i] = *(const bf16x8*)(As + (wm * 64 + i * 16 + li) * 32 + g * 8);
    #pragma unroll
    for (int i = 0; i < 4; ++i)
      bfr[i] = *(const bf16x8*)(Bs + (wn * 64 + i * 16 + li) * 32 + g * 8);
    #pragma unroll
    for (int i = 0; i < 4; ++i)
      #pragma unroll
      for (int j = 0; j < 4; ++j)
        acc[i][j] = __builtin_amdgcn_mfma_f32_16x16x32_bf16(af[i], bfr[j], acc[i][j], 0, 0, 0);
    __syncthreads();
  }

  float bcol[4];
  #pragma unroll
  for (int j = 0; j < 4; ++j) bcol[j] = bias[n0 + wn * 64 + j * 16 + li];

  #pragma unroll
  for (int i = 0; i < 4; ++i) {
    #pragma unroll
    for (int j = 0; j < 4; ++j) {
      #pragma unroll
      for (int r = 0; r < 4; ++r) {
        int row = m0 + wm * 64 + i * 16 + g * 4 + r;
        int col = n0 + wn * 64 + j * 16 + li;
        float v = acc[i][j][r] + bcol[j];
        if (RELU) v = fmaxf(v, 0.f);
        if (OMODE == 0) {
          ((u16*)out0)[(size_t)row * N + col] = f2bf(v);
        } else if (OMODE == 1) {
          ((float*)out0)[(size_t)row * N + col] = v;
        } else {
          int which = col >> 10, hh = (col >> 6) & 15, d = col & 63;
          int bb = row >> 11, ss = row & 2047;
          u16* dst = which == 0 ? (u16*)out0 : (which == 1 ? (u16*)out1 : (u16*)out2);
          dst[((size_t)((bb * 16 + hh) * 2048 + ss)) * 64 + d] = f2bf(v);
        }
      }
    }
  }
}

// ---------------- Flash attention (causal) ----------------
// grid (SEQ/64, B*H), 256 threads = 4 waves; wave w owns q-rows [qtile*64+w*16, +16)
#define NEG_INF -1e30f
__global__ __launch_bounds__(256) void k_attn(
    const u16* __restrict__ Q, const u16* __restrict__ K,
    const u16* __restrict__ V, u16* __restrict__ ctx) {
  const int qtile = blockIdx.x;
  const int bh = blockIdx.y;
  const int b = bh >> 4, h = bh & 15;
  const int tid = threadIdx.x;
  const int wid = tid >> 6, lane = tid & 63, g = lane >> 4, li = lane & 15;

  __shared__ u16 Ks[64 * 80];
  __shared__ u16 Vt[64 * 80];
  __shared__ u16 Pl[4][16 * 80];

  const size_t base = (size_t)bh * SEQ * HDIM;
  const int qrow0 = qtile * 64 + wid * 16;

  bf16x8 qf[2];
  #pragma unroll
  for (int ks = 0; ks < 2; ++ks)
    qf[ks] = *(const bf16x8*)(Q + base + (size_t)(qrow0 + li) * HDIM + ks * 32 + g * 8);

  f32x4 po[4] = {};
  float m_run[4], l_run[4];
  #pragma unroll
  for (int r = 0; r < 4; ++r) { m_run[r] = NEG_INF; l_run[r] = 0.f; }

  const int ntiles = qtile + 1;
  for (int kt = 0; kt < ntiles; ++kt) {
    __syncthreads();  // protect Ks/Vt from previous iteration's readers
    #pragma unroll
    for (int rr = 0; rr < 2; ++rr) {
      int row = rr * 32 + (tid >> 3);
      int c8 = (tid & 7) * 8;
      bf16x8 kv = *(const bf16x8*)(K + base + (size_t)(kt * 64 + row) * HDIM + c8);
      *(bf16x8*)(Ks + row * 80 + c8) = kv;
      bf16x8 vv = *(const bf16x8*)(V + base + (size_t)(kt * 64 + row) * HDIM + c8);
      #pragma unroll
      for (int j = 0; j < 8; ++j) Vt[(c8 + j) * 80 + row] = (u16)vv[j];
    }
    __syncthreads();

    // S = Q K^T for this wave's 16 q-rows x 64 k
    f32x4 sa[4] = {};
    #pragma unroll
    for (int n = 0; n < 4; ++n)
      #pragma unroll
      for (int ks = 0; ks < 2; ++ks) {
        bf16x8 kf = *(const bf16x8*)(Ks + (n * 16 + li) * 80 + ks * 32 + g * 8);
        sa[n] = __builtin_amdgcn_mfma_f32_16x16x32_bf16(qf[ks], kf, sa[n], 0, 0, 0);
      }

    float pv[4][4];
    float mt[4];
    #pragma unroll
    for (int r = 0; r < 4; ++r) mt[r] = NEG_INF;
    #pragma unroll
    for (int n = 0; n < 4; ++n)
      #pragma unroll
      for (int r = 0; r < 4; ++r) {
        float s = sa[n][r] * 0.125f;
        int kg = kt * 64 + n * 16 + li;
        int qg = qtile * 64 + wid * 16 + g * 4 + r;
        if (kg > qg) s = NEG_INF;
        pv[n][r] = s;
        mt[r] = fmaxf(mt[r], s);
      }
    #pragma unroll
    for (int r = 0; r < 4; ++r)
      #pragma unroll
      for (int m = 1; m < 16; m <<= 1) mt[r] = fmaxf(mt[r], __shfl_xor(mt[r], m, 64));

    float lt[4];
    #pragma unroll
    for (int r = 0; r < 4; ++r) {
      float mn = fmaxf(m_run[r], mt[r]);
      float al = __expf(m_run[r] - mn);
      m_run[r] = mn;
      float s = 0.f;
      #pragma unroll
      for (int n = 0; n < 4; ++n) {
        float p = __expf(pv[n][r] - mn);
        pv[n][r] = p;
        s += p;
      }
      lt[r] = s;
      l_run[r] *= al;
      #pragma unroll
      for (int n = 0; n < 4; ++n) po[n][r] *= al;
    }
    #pragma unroll
    for (int r = 0; r < 4; ++r) {
      #pragma unroll
      for (int m = 1; m < 16; m <<= 1) lt[r] += __shfl_xor(lt[r], m, 64);
      l_run[r] += lt[r];
    }

    // P -> per-wave LDS (bf16) in [q][k] layout
    #pragma unroll
    for (int n = 0; n < 4; ++n)
      #pragma unroll
      for (int r = 0; r < 4; ++r)
        Pl[wid][(g * 4 + r) * 80 + n * 16 + li] = f2bf(pv[n][r]);
    __syncthreads();  // orders P writes before cross-lane P reads

    // O += P V
    #pragma unroll
    for (int ks = 0; ks < 2; ++ks) {
      bf16x8 pa = *(const bf16x8*)(Pl[wid] + li * 80 + ks * 32 + g * 8);
      #pragma unroll
      for (int n = 0; n < 4; ++n) {
        bf16x8 vf = *(const bf16x8*)(Vt + (n * 16 + li) * 80 + ks * 32 + g * 8);
        po[n] = __builtin_amdgcn_mfma_f32_16x16x32_bf16(pa, vf, po[n], 0, 0, 0);
      }
    }
  }

  // epilogue: write ctx [B,S,E] bf16
  #pragma unroll
  for (int n = 0; n < 4; ++n)
    #pragma unroll
    for (int r = 0; r < 4; ++r) {
      float o = po[n][r] / l_run[r];
      int row = b * SEQ + qtile * 64 + wid * 16 + g * 4 + r;
      int col = h * HDIM + n * 16 + li;
      ctx[(size_t)row * EMBED + col] = f2bf(o);
    }
}

// ---------------- fused residual-add + LayerNorm ----------------
__global__ __launch_bounds__(256) void k_add_ln(
    const float* __restrict__ a, const float* __restrict__ bmat,
    const float* __restrict__ gam, const float* __restrict__ bet,
    float* __restrict__ outf, u16* __restrict__ outb) {
  const int row = blockIdx.x;
  const int t = threadIdx.x;
  __shared__ float red[8];
  float4 va = ((const float4*)(a + (size_t)row * EMBED))[t];
  float4 vb = ((const float4*)(bmat + (size_t)row * EMBED))[t];
  float s0 = va.x + vb.x, s1 = va.y + vb.y, s2 = va.z + vb.z, s3 = va.w + vb.w;
  float sum = s0 + s1 + s2 + s3;
  float sq = s0 * s0 + s1 * s1 + s2 * s2 + s3 * s3;
  #pragma unroll
  for (int m = 1; m < 64; m <<= 1) {
    sum += __shfl_xor(sum, m, 64);
    sq += __shfl_xor(sq, m, 64);
  }
  int wid = t >> 6;
  if ((t & 63) == 0) { red[wid] = sum; red[4 + wid] = sq; }
  __syncthreads();
  sum = red[0] + red[1] + red[2] + red[3];
  sq = red[4] + red[5] + red[6] + red[7];
  float mean = sum * (1.f / EMBED);
  float var = sq * (1.f / EMBED) - mean * mean;
  float rstd = rsqrtf(var + 1e-5f);
  float4 gv = ((const float4*)gam)[t], bev = ((const float4*)bet)[t];
  float y0 = (s0 - mean) * rstd * gv.x + bev.x;
  float y1 = (s1 - mean) * rstd * gv.y + bev.y;
  float y2 = (s2 - mean) * rstd * gv.z + bev.z;
  float y3 = (s3 - mean) * rstd * gv.w + bev.w;
  float4 o; o.x = y0; o.y = y1; o.z = y2; o.w = y3;
  ((float4*)(outf + (size_t)row * EMBED))[t] = o;
  if (outb) {
    ushort4 ob; ob.x = f2bf(y0); ob.y = f2bf(y1); ob.z = f2bf(y2); ob.w = f2bf(y3);
    ((ushort4*)(outb + (size_t)row * EMBED))[t] = ob;
  }
}

extern "C" void kernel_launch(void* const* d_in, const int* in_sizes, int n_in,
                              void* d_out, int out_size, void* d_ws, size_t ws_size,
                              hipStream_t stream) {
  const float* x      = (const float*)d_in[0];
  const float* w_qkv  = (const float*)d_in[1];
  const float* b_qkv  = (const float*)d_in[2];
  const float* w_out  = (const float*)d_in[3];
  const float* b_out  = (const float*)d_in[4];
  const float* w_up   = (const float*)d_in[5];
  const float* b_up   = (const float*)d_in[6];
  const float* w_down = (const float*)d_in[7];
  const float* b_down = (const float*)d_in[8];
  const float* g1  = (const float*)d_in[9];
  const float* be1 = (const float*)d_in[10];
  const float* g2  = (const float*)d_in[11];
  const float* be2 = (const float*)d_in[12];

  char* ws = (char*)d_ws;
  size_t off = 0;
  auto alloc = [&](size_t bytes) { void* p = ws + off; off += (bytes + 255) & ~(size_t)255; return p; };

  u16* xb     = (u16*)alloc((size_t)MTOT * EMBED * 2);
  u16* wqkvT  = (u16*)alloc((size_t)3 * EMBED * EMBED * 2);
  u16* woutT  = (u16*)alloc((size_t)EMBED * EMBED * 2);
  u16* wupT   = (u16*)alloc((size_t)FFN * EMBED * 2);
  u16* wdownT = (u16*)alloc((size_t)EMBED * FFN * 2);
  u16* qb     = (u16*)alloc((size_t)MTOT * EMBED * 2);
  u16* kb     = (u16*)alloc((size_t)MTOT * EMBED * 2);
  u16* vb     = (u16*)alloc((size_t)MTOT * EMBED * 2);
  u16* ctx    = (u16*)alloc((size_t)MTOT * EMBED * 2);
  float* attn_proj = (float*)alloc((size_t)MTOT * EMBED * 4);
  float* y_f32     = (float*)alloc((size_t)MTOT * EMBED * 4);
  u16* y_bf16      = (u16*)alloc((size_t)MTOT * EMBED * 2);
  u16* hmid        = (u16*)alloc((size_t)MTOT * FFN * 2);
  float* ffn_o     = (float*)alloc((size_t)MTOT * EMBED * 4);

  dim3 trb(32, 8);
  k_cvt<<<2048, 256, 0, stream>>>(x, xb, MTOT * EMBED / 4);
  k_tr<<<dim3(3 * EMBED / 32, EMBED / 32), trb, 0, stream>>>(w_qkv, wqkvT, EMBED, 3 * EMBED);
  k_tr<<<dim3(EMBED / 32, EMBED / 32), trb, 0, stream>>>(w_out, woutT, EMBED, EMBED);
  k_tr<<<dim3(FFN / 32, EMBED / 32), trb, 0, stream>>>(w_up, wupT, EMBED, FFN);
  k_tr<<<dim3(EMBED / 32, FFN / 32), trb, 0, stream>>>(w_down, wdownT, FFN, EMBED);

  k_gemm<2, false><<<dim3(3 * EMBED / 128, MTOT / 128), 256, 0, stream>>>(
      xb, wqkvT, b_qkv, qb, kb, vb, MTOT, 3 * EMBED, EMBED);

  k_attn<<<dim3(SEQ / 64, BATCH * HEADS), 256, 0, stream>>>(qb, kb, vb, ctx);

  k_gemm<1, false><<<dim3(EMBED / 128, MTOT / 128), 256, 0, stream>>>(
      ctx, woutT, b_out, attn_proj, nullptr, nullptr, MTOT, EMBED, EMBED);

  k_add_ln<<<MTOT, 256, 0, stream>>>(x, attn_proj, g1, be1, y_f32, y_bf16);

  k_gemm<0, true><<<dim3(FFN / 128, MTOT / 128), 256, 0, stream>>>(
      y_bf16, wupT, b_up, hmid, nullptr, nullptr, MTOT, FFN, EMBED);

  k_gemm<1, false><<<dim3(EMBED / 128, MTOT / 128), 256, 0, stream>>>(
      hmid, wdownT, b_down, ffn_o, nullptr, nullptr, MTOT, EMBED, FFN);

  k_add_ln<<<MTOT, 256, 0, stream>>>(y_f32, ffn_o, g2, be2, (float*)d_out, nullptr);

  (void)in_sizes; (void)n_in; (void)out_size; (void)ws_size;
}

// Round 2
// 367.613 us; speedup vs baseline: 1.1243x; 1.1243x over previous
//
#include <hip/hip_runtime.h>
#include <hip/hip_bf16.h>

#define EMBED 1024
#define HEADS 16
#define HDIM 64
#define FFN 4096
#define SEQ 2048
#define BATCH 2
#define MTOT (BATCH*SEQ)

typedef __attribute__((ext_vector_type(8))) short bf16x8;
typedef __attribute__((ext_vector_type(4))) float f32x4;
typedef unsigned short u16;

__device__ __forceinline__ u16 f2bf(float f) {
  union { float f; unsigned u; } v; v.f = f;
  unsigned r = v.u + 0x7FFFu + ((v.u >> 16) & 1u);
  return (u16)(r >> 16);
}

__device__ __forceinline__ void async_ld16(const void* g, void* l) {
  __builtin_amdgcn_global_load_lds((const __attribute__((address_space(1))) void*)g,
                                   (__attribute__((address_space(3))) void*)l,
                                   16, 0, 0);
}

// ---------------- fp32 -> bf16 convert (vectorized) ----------------
__global__ __launch_bounds__(256) void k_cvt(const float* __restrict__ in,
                                             u16* __restrict__ out, int n4) {
  int i = blockIdx.x * 256 + threadIdx.x;
  int st = gridDim.x * 256;
  for (; i < n4; i += st) {
    float4 v = ((const float4*)in)[i];
    ushort4 o;
    o.x = f2bf(v.x); o.y = f2bf(v.y); o.z = f2bf(v.z); o.w = f2bf(v.w);
    ((ushort4*)out)[i] = o;
  }
}

// ---------------- transpose-convert: w[K,N] fp32 -> wT[N,K] bf16 ----------------
__global__ __launch_bounds__(256) void k_tr(const float* __restrict__ w,
                                            u16* __restrict__ wT, int K, int N) {
  __shared__ u16 tile[32][33];
  int n0 = blockIdx.x * 32, k0 = blockIdx.y * 32;
  int tx = threadIdx.x, ty = threadIdx.y;   // blockDim (32,8)
  #pragma unroll
  for (int i = 0; i < 4; ++i) {
    int k = k0 + ty + i * 8;
    tile[ty + i * 8][tx] = f2bf(w[(size_t)k * N + n0 + tx]);
  }
  __syncthreads();
  #pragma unroll
  for (int i = 0; i < 4; ++i) {
    int n = n0 + ty + i * 8;
    wT[(size_t)n * K + k0 + tx] = tile[tx][ty + i * 8];
  }
}

// ---------------- bf16 transpose: V [BH, S, 64] -> Vt [BH, 64, S] ----------------
__global__ __launch_bounds__(256) void k_vtr(const u16* __restrict__ V,
                                             u16* __restrict__ Vt) {
  __shared__ u16 t[64][72];   // [d][s]
  const int s0 = blockIdx.x * 64;
  const size_t ib = (size_t)blockIdx.y * (size_t)SEQ * HDIM;
  const size_t ob = (size_t)blockIdx.y * (size_t)HDIM * SEQ;
  const int tid = threadIdx.x;
  const int r = tid >> 2, c0 = (tid & 3) * 16;
  bf16x8 v0 = *(const bf16x8*)(V + ib + (size_t)(s0 + r) * HDIM + c0);
  bf16x8 v1 = *(const bf16x8*)(V + ib + (size_t)(s0 + r) * HDIM + c0 + 8);
  #pragma unroll
  for (int j = 0; j < 8; ++j) {
    t[c0 + j][r] = (u16)v0[j];
    t[c0 + 8 + j][r] = (u16)v1[j];
  }
  __syncthreads();
  const int d = tid >> 2, sc = (tid & 3) * 16;
  bf16x8 o0, o1;
  #pragma unroll
  for (int j = 0; j < 8; ++j) { o0[j] = t[d][sc + j]; o1[j] = t[d][sc + 8 + j]; }
  *(bf16x8*)(Vt + ob + (size_t)d * SEQ + s0 + sc) = o0;
  *(bf16x8*)(Vt + ob + (size_t)d * SEQ + s0 + sc + 8) = o1;
}

// ---------------- MFMA GEMM: C[M,N] = A[M,K] @ BT[N,K]^T + bias ----------------
// OMODE: 0 = bf16 out [M,N], 1 = f32 out [M,N], 2 = QKV scatter to [B,H,S,D] bf16
template <int OMODE, bool RELU>
__global__ __launch_bounds__(256) void k_gemm(
    const u16* __restrict__ A, const u16* __restrict__ BT,
    const float* __restrict__ bias,
    void* __restrict__ out0, void* __restrict__ out1, void* __restrict__ out2,
    int M, int N, int K) {
  __shared__ u16 As[128 * 32];
  __shared__ u16 Bs[128 * 32];
  const int tid = threadIdx.x;
  const int lane = tid & 63, g = lane >> 4, li = lane & 15;
  const int wid = tid >> 6, wm = wid >> 1, wn = wid & 1;
  const int m0 = blockIdx.y * 128, n0 = blockIdx.x * 128;

  f32x4 acc[4][4] = {};

  const u16* Ablk = A + (size_t)m0 * K;
  const u16* Bblk = BT + (size_t)n0 * K;
  const int arow = tid >> 2, acol = (tid & 3) * 8;

  for (int kt = 0; kt < K; kt += 32) {
    async_ld16(Ablk + (size_t)arow * K + kt + acol, As + tid * 8);
    async_ld16(Ablk + (size_t)(arow + 64) * K + kt + acol, As + 2048 + tid * 8);
    async_ld16(Bblk + (size_t)arow * K + kt + acol, Bs + tid * 8);
    async_ld16(Bblk + (size_t)(arow + 64) * K + kt + acol, Bs + 2048 + tid * 8);
    __syncthreads();
    bf16x8 af[4], bfr[4];
    #pragma unroll
    for (int i = 0; i < 4; ++i)
      af[i] = *(const bf16x8*)(As + (wm * 64 + i * 16 + li) * 32 + g * 8);
    #pragma unroll
    for (int i = 0; i < 4; ++i)
      bfr[i] = *(const bf16x8*)(Bs + (wn * 64 + i * 16 + li) * 32 + g * 8);
    #pragma unroll
    for (int i = 0; i < 4; ++i)
      #pragma unroll
      for (int j = 0; j < 4; ++j)
        acc[i][j] = __builtin_amdgcn_mfma_f32_16x16x32_bf16(af[i], bfr[j], acc[i][j], 0, 0, 0);
    __syncthreads();
  }

  float bcol[4];
  #pragma unroll
  for (int j = 0; j < 4; ++j) bcol[j] = bias[n0 + wn * 64 + j * 16 + li];

  #pragma unroll
  for (int i = 0; i < 4; ++i) {
    #pragma unroll
    for (int j = 0; j < 4; ++j) {
      #pragma unroll
      for (int r = 0; r < 4; ++r) {
        int row = m0 + wm * 64 + i * 16 + g * 4 + r;
        int col = n0 + wn * 64 + j * 16 + li;
        float v = acc[i][j][r] + bcol[j];
        if (RELU) v = fmaxf(v, 0.f);
        if (OMODE == 0) {
          ((u16*)out0)[(size_t)row * N + col] = f2bf(v);
        } else if (OMODE == 1) {
          ((float*)out0)[(size_t)row * N + col] = v;
        } else {
          int which = col >> 10, hh = (col >> 6) & 15, d = col & 63;
          int bb = row >> 11, ss = row & 2047;
          u16* dst = which == 0 ? (u16*)out0 : (which == 1 ? (u16*)out1 : (u16*)out2);
          dst[((size_t)((bb * 16 + hh) * 2048 + ss)) * 64 + d] = f2bf(v);
        }
      }
    }
  }
}

// ---------------- Flash attention (causal), 8 waves, 128 q-rows/block ----------------
// K: [BH,S,D] row-major; Vt: [BH,D,S] (pre-transposed). Both staged to linear
// [64][64] u16 LDS tiles via global_load_lds with XOR-swizzled (chunk ^ row&7)
// global source; fragment reads apply the same XOR -> conflict-free ds_read_b128.
#define NEG_INF -1e30f
__global__ __launch_bounds__(512) void k_attn2(
    const u16* __restrict__ Q, const u16* __restrict__ K,
    const u16* __restrict__ Vt, u16* __restrict__ ctx) {
  const int qb = (int)gridDim.x - 1 - (int)blockIdx.x;  // largest-first
  const int bh = blockIdx.y;
  const int b = bh >> 4, h = bh & 15;
  const int tid = threadIdx.x;
  const int wid = tid >> 6, lane = tid & 63, g = lane >> 4, li = lane & 15;

  __shared__ u16 Ks[64 * 64];
  __shared__ u16 Vs[64 * 64];
  __shared__ u16 Pl[8][16 * 72];

  const size_t kbase = (size_t)bh * SEQ * HDIM;   // Q,K: [BH,S,D]
  const size_t vbase = (size_t)bh * HDIM * SEQ;   // Vt:  [BH,D,S]
  const int qrow0 = qb * 128 + wid * 16;

  bf16x8 qf[2];
  #pragma unroll
  for (int ks = 0; ks < 2; ++ks)
    qf[ks] = *(const bf16x8*)(Q + kbase + (size_t)(qrow0 + li) * HDIM + ks * 32 + g * 8);

  f32x4 po[4] = {};
  float m_run[4], l_run[4];
  #pragma unroll
  for (int r = 0; r < 4; ++r) { m_run[r] = NEG_INF; l_run[r] = 0.f; }

  // staging: 512 threads x 16B = one 8KB tile per issue; thread -> chunk tid
  const int srow = tid >> 3;                       // tile row (s for K, d for Vt)
  const int scol = ((tid & 7) ^ (srow & 7)) * 8;   // swizzled 16B-chunk within row
  const u16* Kg = K + kbase + scol;
  const u16* Vg = Vt + vbase + (size_t)srow * SEQ + scol;

  const int ntiles = 2 * qb + 2;
  for (int kt = 0; kt < ntiles; ++kt) {
    __syncthreads();  // prev tile's readers done before restage
    async_ld16(Kg + (size_t)(kt * 64 + srow) * HDIM, Ks + tid * 8);
    async_ld16(Vg + kt * 64, Vs + tid * 8);
    __syncthreads();  // staged data visible

    // S = Q K^T  (16 q-rows x 64 k per wave)
    f32x4 sa[4] = {};
    #pragma unroll
    for (int n = 0; n < 4; ++n) {
      const int row = n * 16 + li;
      #pragma unroll
      for (int ks = 0; ks < 2; ++ks) {
        const int c = ks * 4 + g;
        bf16x8 kf = *(const bf16x8*)(Ks + row * 64 + ((c ^ (row & 7)) * 8));
        sa[n] = __builtin_amdgcn_mfma_f32_16x16x32_bf16(qf[ks], kf, sa[n], 0, 0, 0);
      }
    }

    // online softmax (wave-parallel, 16-lane groups)
    float pv[4][4];
    float mt[4];
    #pragma unroll
    for (int r = 0; r < 4; ++r) mt[r] = NEG_INF;
    #pragma unroll
    for (int n = 0; n < 4; ++n)
      #pragma unroll
      for (int r = 0; r < 4; ++r) {
        float s = sa[n][r] * 0.125f;
        int kg = kt * 64 + n * 16 + li;
        int qg = qrow0 + g * 4 + r;
        if (kg > qg) s = NEG_INF;
        pv[n][r] = s;
        mt[r] = fmaxf(mt[r], s);
      }
    #pragma unroll
    for (int r = 0; r < 4; ++r)
      #pragma unroll
      for (int m = 1; m < 16; m <<= 1) mt[r] = fmaxf(mt[r], __shfl_xor(mt[r], m, 64));

    float lt[4];
    #pragma unroll
    for (int r = 0; r < 4; ++r) {
      float mn = fmaxf(m_run[r], mt[r]);
      float al = __expf(m_run[r] - mn);
      m_run[r] = mn;
      float s = 0.f;
      #pragma unroll
      for (int n = 0; n < 4; ++n) {
        float p = __expf(pv[n][r] - mn);
        pv[n][r] = p;
        s += p;
      }
      lt[r] = s;
      l_run[r] *= al;
      #pragma unroll
      for (int n = 0; n < 4; ++n) po[n][r] *= al;
    }
    #pragma unroll
    for (int r = 0; r < 4; ++r) {
      #pragma unroll
      for (int m = 1; m < 16; m <<= 1) lt[r] += __shfl_xor(lt[r], m, 64);
      l_run[r] += lt[r];
    }

    // P -> per-wave LDS (bf16), stride 72 (2-way-free reads)
    #pragma unroll
    for (int n = 0; n < 4; ++n)
      #pragma unroll
      for (int r = 0; r < 4; ++r)
        Pl[wid][(g * 4 + r) * 72 + n * 16 + li] = f2bf(pv[n][r]);
    __syncthreads();  // cross-lane P visibility

    // O += P V  (Vs holds V^T tile: row d, k contiguous, swizzled)
    #pragma unroll
    for (int ks = 0; ks < 2; ++ks) {
      bf16x8 pa = *(const bf16x8*)(Pl[wid] + li * 72 + ks * 32 + g * 8);
      #pragma unroll
      for (int n = 0; n < 4; ++n) {
        const int row = n * 16 + li;
        const int c = ks * 4 + g;
        bf16x8 vf = *(const bf16x8*)(Vs + row * 64 + ((c ^ (row & 7)) * 8));
        po[n] = __builtin_amdgcn_mfma_f32_16x16x32_bf16(pa, vf, po[n], 0, 0, 0);
      }
    }
  }

  // epilogue: ctx [B*S, E] bf16
  #pragma unroll
  for (int n = 0; n < 4; ++n)
    #pragma unroll
    for (int r = 0; r < 4; ++r) {
      float o = po[n][r] / l_run[r];
      int row = b * SEQ + qb * 128 + wid * 16 + g * 4 + r;
      int col = h * HDIM + n * 16 + li;
      ctx[(size_t)row * EMBED + col] = f2bf(o);
    }
}

// ---------------- fused residual-add + LayerNorm ----------------
__global__ __launch_bounds__(256) void k_add_ln(
    const float* __restrict__ a, const float* __restrict__ bmat,
    const float* __restrict__ gam, const float* __restrict__ bet,
    float* __restrict__ outf, u16* __restrict__ outb) {
  const int row = blockIdx.x;
  const int t = threadIdx.x;
  __shared__ float red[8];
  float4 va = ((const float4*)(a + (size_t)row * EMBED))[t];
  float4 vb = ((const float4*)(bmat + (size_t)row * EMBED))[t];
  float s0 = va.x + vb.x, s1 = va.y + vb.y, s2 = va.z + vb.z, s3 = va.w + vb.w;
  float sum = s0 + s1 + s2 + s3;
  float sq = s0 * s0 + s1 * s1 + s2 * s2 + s3 * s3;
  #pragma unroll
  for (int m = 1; m < 64; m <<= 1) {
    sum += __shfl_xor(sum, m, 64);
    sq += __shfl_xor(sq, m, 64);
  }
  int wid = t >> 6;
  if ((t & 63) == 0) { red[wid] = sum; red[4 + wid] = sq; }
  __syncthreads();
  sum = red[0] + red[1] + red[2] + red[3];
  sq = red[4] + red[5] + red[6] + red[7];
  float mean = sum * (1.f / EMBED);
  float var = sq * (1.f / EMBED) - mean * mean;
  float rstd = rsqrtf(var + 1e-5f);
  float4 gv = ((const float4*)gam)[t], bev = ((const float4*)bet)[t];
  float y0 = (s0 - mean) * rstd * gv.x + bev.x;
  float y1 = (s1 - mean) * rstd * gv.y + bev.y;
  float y2 = (s2 - mean) * rstd * gv.z + bev.z;
  float y3 = (s3 - mean) * rstd * gv.w + bev.w;
  float4 o; o.x = y0; o.y = y1; o.z = y2; o.w = y3;
  ((float4*)(outf + (size_t)row * EMBED))[t] = o;
  if (outb) {
    ushort4 ob; ob.x = f2bf(y0); ob.y = f2bf(y1); ob.z = f2bf(y2); ob.w = f2bf(y3);
    ((ushort4*)(outb + (size_t)row * EMBED))[t] = ob;
  }
}

extern "C" void kernel_launch(void* const* d_in, const int* in_sizes, int n_in,
                              void* d_out, int out_size, void* d_ws, size_t ws_size,
                              hipStream_t stream) {
  const float* x      = (const float*)d_in[0];
  const float* w_qkv  = (const float*)d_in[1];
  const float* b_qkv  = (const float*)d_in[2];
  const float* w_out  = (const float*)d_in[3];
  const float* b_out  = (const float*)d_in[4];
  const float* w_up   = (const float*)d_in[5];
  const float* b_up   = (const float*)d_in[6];
  const float* w_down = (const float*)d_in[7];
  const float* b_down = (const float*)d_in[8];
  const float* g1  = (const float*)d_in[9];
  const float* be1 = (const float*)d_in[10];
  const float* g2  = (const float*)d_in[11];
  const float* be2 = (const float*)d_in[12];

  char* ws = (char*)d_ws;
  size_t off = 0;
  auto alloc = [&](size_t bytes) { void* p = ws + off; off += (bytes + 255) & ~(size_t)255; return p; };

  u16* xb     = (u16*)alloc((size_t)MTOT * EMBED * 2);
  u16* wqkvT  = (u16*)alloc((size_t)3 * EMBED * EMBED * 2);
  u16* woutT  = (u16*)alloc((size_t)EMBED * EMBED * 2);
  u16* wupT   = (u16*)alloc((size_t)FFN * EMBED * 2);
  u16* wdownT = (u16*)alloc((size_t)EMBED * FFN * 2);
  u16* qb     = (u16*)alloc((size_t)MTOT * EMBED * 2);
  u16* kb     = (u16*)alloc((size_t)MTOT * EMBED * 2);
  u16* vb     = (u16*)alloc((size_t)MTOT * EMBED * 2);
  u16* vtb    = (u16*)alloc((size_t)MTOT * EMBED * 2);
  u16* ctx    = (u16*)alloc((size_t)MTOT * EMBED * 2);
  float* attn_proj = (float*)alloc((size_t)MTOT * EMBED * 4);
  float* y_f32     = (float*)alloc((size_t)MTOT * EMBED * 4);
  u16* y_bf16      = (u16*)alloc((size_t)MTOT * EMBED * 2);
  u16* hmid        = (u16*)alloc((size_t)MTOT * FFN * 2);
  float* ffn_o     = (float*)alloc((size_t)MTOT * EMBED * 4);

  dim3 trb(32, 8);
  k_cvt<<<2048, 256, 0, stream>>>(x, xb, MTOT * EMBED / 4);
  k_tr<<<dim3(3 * EMBED / 32, EMBED / 32), trb, 0, stream>>>(w_qkv, wqkvT, EMBED, 3 * EMBED);
  k_tr<<<dim3(EMBED / 32, EMBED / 32), trb, 0, stream>>>(w_out, woutT, EMBED, EMBED);
  k_tr<<<dim3(FFN / 32, EMBED / 32), trb, 0, stream>>>(w_up, wupT, EMBED, FFN);
  k_tr<<<dim3(EMBED / 32, FFN / 32), trb, 0, stream>>>(w_down, wdownT, FFN, EMBED);

  k_gemm<2, false><<<dim3(3 * EMBED / 128, MTOT / 128), 256, 0, stream>>>(
      xb, wqkvT, b_qkv, qb, kb, vb, MTOT, 3 * EMBED, EMBED);

  k_vtr<<<dim3(SEQ / 64, BATCH * HEADS), 256, 0, stream>>>(vb, vtb);

  k_attn2<<<dim3(SEQ / 128, BATCH * HEADS), 512, 0, stream>>>(qb, kb, vtb, ctx);

  k_gemm<1, false><<<dim3(EMBED / 128, MTOT / 128), 256, 0, stream>>>(
      ctx, woutT, b_out, attn_proj, nullptr, nullptr, MTOT, EMBED, EMBED);

  k_add_ln<<<MTOT, 256, 0, stream>>>(x, attn_proj, g1, be1, y_f32, y_bf16);

  k_gemm<0, true><<<dim3(FFN / 128, MTOT / 128), 256, 0, stream>>>(
      y_bf16, wupT, b_up, hmid, nullptr, nullptr, MTOT, FFN, EMBED);

  k_gemm<1, false><<<dim3(EMBED / 128, MTOT / 128), 256, 0, stream>>>(
      hmid, wdownT, b_down, ffn_o, nullptr, nullptr, MTOT, EMBED, FFN);

  k_add_ln<<<MTOT, 256, 0, stream>>>(y_f32, ffn_o, g2, be2, (float*)d_out, nullptr);

  (void)in_sizes; (void)n_in; (void)out_size; (void)ws_size;
}

// Round 3
// 311.061 us; speedup vs baseline: 1.3287x; 1.1818x over previous
//
#include <hip/hip_runtime.h>
#include <hip/hip_bf16.h>

#define EMBED 1024
#define HEADS 16
#define HDIM 64
#define FFN 4096
#define SEQ 2048
#define BATCH 2
#define MTOT (BATCH*SEQ)

typedef __attribute__((ext_vector_type(8))) short bf16x8;
typedef __attribute__((ext_vector_type(4))) float f32x4;
typedef unsigned short u16;

__device__ __forceinline__ u16 f2bf(float f) {
  union { float f; unsigned u; } v; v.f = f;
  unsigned r = v.u + 0x7FFFu + ((v.u >> 16) & 1u);
  return (u16)(r >> 16);
}

__device__ __forceinline__ void async_ld16(const void* g, void* l) {
  __builtin_amdgcn_global_load_lds((const __attribute__((address_space(1))) void*)g,
                                   (__attribute__((address_space(3))) void*)l,
                                   16, 0, 0);
}

// ---------------- fp32 -> bf16 convert (vectorized) ----------------
__global__ __launch_bounds__(256) void k_cvt(const float* __restrict__ in,
                                             u16* __restrict__ out, int n4) {
  int i = blockIdx.x * 256 + threadIdx.x;
  int st = gridDim.x * 256;
  for (; i < n4; i += st) {
    float4 v = ((const float4*)in)[i];
    ushort4 o;
    o.x = f2bf(v.x); o.y = f2bf(v.y); o.z = f2bf(v.z); o.w = f2bf(v.w);
    ((ushort4*)out)[i] = o;
  }
}

// ---------------- transpose-convert: w[K,N] fp32 -> wT[N,K] bf16 ----------------
__global__ __launch_bounds__(256) void k_tr(const float* __restrict__ w,
                                            u16* __restrict__ wT, int K, int N) {
  __shared__ u16 tile[32][33];
  int n0 = blockIdx.x * 32, k0 = blockIdx.y * 32;
  int tx = threadIdx.x, ty = threadIdx.y;   // blockDim (32,8)
  #pragma unroll
  for (int i = 0; i < 4; ++i) {
    int k = k0 + ty + i * 8;
    tile[ty + i * 8][tx] = f2bf(w[(size_t)k * N + n0 + tx]);
  }
  __syncthreads();
  #pragma unroll
  for (int i = 0; i < 4; ++i) {
    int n = n0 + ty + i * 8;
    wT[(size_t)n * K + k0 + tx] = tile[tx][ty + i * 8];
  }
}

// ---------------- bf16 transpose: V [BH, S, 64] -> Vt [BH, 64, S] ----------------
__global__ __launch_bounds__(256) void k_vtr(const u16* __restrict__ V,
                                             u16* __restrict__ Vt) {
  __shared__ u16 t[64][72];   // [d][s]
  const int s0 = blockIdx.x * 64;
  const size_t ib = (size_t)blockIdx.y * (size_t)SEQ * HDIM;
  const size_t ob = (size_t)blockIdx.y * (size_t)HDIM * SEQ;
  const int tid = threadIdx.x;
  const int r = tid >> 2, c0 = (tid & 3) * 16;
  bf16x8 v0 = *(const bf16x8*)(V + ib + (size_t)(s0 + r) * HDIM + c0);
  bf16x8 v1 = *(const bf16x8*)(V + ib + (size_t)(s0 + r) * HDIM + c0 + 8);
  #pragma unroll
  for (int j = 0; j < 8; ++j) {
    t[c0 + j][r] = (u16)v0[j];
    t[c0 + 8 + j][r] = (u16)v1[j];
  }
  __syncthreads();
  const int d = tid >> 2, sc = (tid & 3) * 16;
  bf16x8 o0, o1;
  #pragma unroll
  for (int j = 0; j < 8; ++j) { o0[j] = t[d][sc + j]; o1[j] = t[d][sc + 8 + j]; }
  *(bf16x8*)(Vt + ob + (size_t)d * SEQ + s0 + sc) = o0;
  *(bf16x8*)(Vt + ob + (size_t)d * SEQ + s0 + sc + 8) = o1;
}

// ---------------- MFMA GEMM: C[M,N] = A[M,K] @ BT[N,K]^T + bias ----------------
// BM=128 fixed, 256 threads (4 waves, 2x2), double-buffered LDS + prefetch.
// XOR-swizzled chunk layout (pre-swizzled global source + swizzled read).
// OMODE: 0 = bf16 out [M,N], 1 = f32 out [M,N], 2 = QKV scatter to [B,H,S,D] bf16
template <int BN, int BK, int OMODE, bool RELU>
__global__ __launch_bounds__(256) void k_gemm(
    const u16* __restrict__ A, const u16* __restrict__ BT,
    const float* __restrict__ bias,
    void* __restrict__ out0, void* __restrict__ out1, void* __restrict__ out2,
    int M, int N, int K) {
  constexpr int NR = BN / 32;          // frags per wave in N (WN=2)
  constexpr int KS = BK / 32;          // 32-wide k-steps per tile
  constexpr int TPR = BK / 8;          // threads (16B chunks) per row
  constexpr int RPI = 256 / TPR;       // rows per load instr
  constexpr int CM = TPR - 1;          // chunk swizzle mask

  __shared__ u16 As[2][128 * BK];
  __shared__ u16 Bs[2][BN * BK];
  const int tid = threadIdx.x;
  const int lane = tid & 63, g = lane >> 4, li = lane & 15;
  const int wid = tid >> 6, wm = wid >> 1, wn = wid & 1;
  const int m0 = blockIdx.y * 128, n0 = blockIdx.x * BN;

  f32x4 acc[4][NR] = {};

  const u16* Ablk = A + (size_t)m0 * K;
  const u16* Bblk = BT + (size_t)n0 * K;
  const int srow = tid / TPR;
  const int scol = ((tid % TPR) ^ (srow & CM)) * 8;   // swizzled source chunk

  auto stage = [&](int buf, int kt) {
    #pragma unroll
    for (int r = 0; r < 128; r += RPI)
      async_ld16(Ablk + (size_t)(srow + r) * K + kt + scol, &As[buf][(srow + r) * BK] + (tid % TPR) * 8);
    #pragma unroll
    for (int r = 0; r < BN; r += RPI)
      async_ld16(Bblk + (size_t)(srow + r) * K + kt + scol, &Bs[buf][(srow + r) * BK] + (tid % TPR) * 8);
  };

  stage(0, 0);
  int cur = 0;
  for (int kt = 0; kt < K; kt += BK) {
    __syncthreads();                  // drains prefetch, frees other buffer
    if (kt + BK < K) stage(cur ^ 1, kt + BK);

    bf16x8 af[4][KS], bfr[NR][KS];
    #pragma unroll
    for (int i = 0; i < 4; ++i) {
      const int row = wm * 64 + i * 16 + li;
      #pragma unroll
      for (int ks = 0; ks < KS; ++ks) {
        const int c = ks * 4 + g;
        af[i][ks] = *(const bf16x8*)(&As[cur][row * BK] + ((c ^ (row & CM)) & CM) * 8);
      }
    }
    #pragma unroll
    for (int j = 0; j < NR; ++j) {
      const int row = wn * (BN / 2) + j * 16 + li;
      #pragma unroll
      for (int ks = 0; ks < KS; ++ks) {
        const int c = ks * 4 + g;
        bfr[j][ks] = *(const bf16x8*)(&Bs[cur][row * BK] + ((c ^ (row & CM)) & CM) * 8);
      }
    }
    #pragma unroll
    for (int ks = 0; ks < KS; ++ks)
      #pragma unroll
      for (int i = 0; i < 4; ++i)
        #pragma unroll
        for (int j = 0; j < NR; ++j)
          acc[i][j] = __builtin_amdgcn_mfma_f32_16x16x32_bf16(af[i][ks], bfr[j][ks], acc[i][j], 0, 0, 0);
    cur ^= 1;
  }

  float bcol[NR];
  #pragma unroll
  for (int j = 0; j < NR; ++j) bcol[j] = bias[n0 + wn * (BN / 2) + j * 16 + li];

  #pragma unroll
  for (int i = 0; i < 4; ++i) {
    #pragma unroll
    for (int j = 0; j < NR; ++j) {
      #pragma unroll
      for (int r = 0; r < 4; ++r) {
        int row = m0 + wm * 64 + i * 16 + g * 4 + r;
        int col = n0 + wn * (BN / 2) + j * 16 + li;
        float v = acc[i][j][r] + bcol[j];
        if (RELU) v = fmaxf(v, 0.f);
        if (OMODE == 0) {
          ((u16*)out0)[(size_t)row * N + col] = f2bf(v);
        } else if (OMODE == 1) {
          ((float*)out0)[(size_t)row * N + col] = v;
        } else {
          int which = col >> 10, hh = (col >> 6) & 15, d = col & 63;
          int bb = row >> 11, ss = row & 2047;
          u16* dst = which == 0 ? (u16*)out0 : (which == 1 ? (u16*)out1 : (u16*)out2);
          dst[((size_t)((bb * 16 + hh) * 2048 + ss)) * 64 + d] = f2bf(v);
        }
      }
    }
  }
}

// ---------------- Flash attention (causal), 8 waves, 128 q-rows/block ----------------
// Double-buffered K/V staging (prefetch t+1 during compute of t), one barrier
// per tile; P-bounce is wave-private (lgkmcnt wait, no barrier).
#define NEG_INF -1e30f
__global__ __launch_bounds__(512) void k_attn2(
    const u16* __restrict__ Q, const u16* __restrict__ K,
    const u16* __restrict__ Vt, u16* __restrict__ ctx) {
  const int qb = (int)gridDim.x - 1 - (int)blockIdx.x;  // largest-first
  const int bh = blockIdx.y;
  const int b = bh >> 4, h = bh & 15;
  const int tid = threadIdx.x;
  const int wid = tid >> 6, lane = tid & 63, g = lane >> 4, li = lane & 15;

  __shared__ u16 Ks[2][64 * 64];
  __shared__ u16 Vs[2][64 * 64];
  __shared__ u16 Pl[8][16 * 72];

  const size_t kbase = (size_t)bh * SEQ * HDIM;   // Q,K: [BH,S,D]
  const size_t vbase = (size_t)bh * HDIM * SEQ;   // Vt:  [BH,D,S]
  const int qrow0 = qb * 128 + wid * 16;

  bf16x8 qf[2];
  #pragma unroll
  for (int ks = 0; ks < 2; ++ks)
    qf[ks] = *(const bf16x8*)(Q + kbase + (size_t)(qrow0 + li) * HDIM + ks * 32 + g * 8);

  f32x4 po[4] = {};
  float m_run[4], l_run[4];
  #pragma unroll
  for (int r = 0; r < 4; ++r) { m_run[r] = NEG_INF; l_run[r] = 0.f; }

  // staging: 512 threads x 16B = one 8KB tile per issue
  const int srow = tid >> 3;                       // tile row (s for K, d for Vt)
  const int scol = ((tid & 7) ^ (srow & 7)) * 8;   // swizzled 16B-chunk in row
  const u16* Kg = K + kbase + scol;
  const u16* Vg = Vt + vbase + (size_t)srow * SEQ + scol;

  const int ntiles = 2 * qb + 2;
  // prologue
  async_ld16(Kg + (size_t)srow * HDIM, &Ks[0][0] + tid * 8);
  async_ld16(Vg, &Vs[0][0] + tid * 8);
  int cur = 0;

  for (int kt = 0; kt < ntiles; ++kt) {
    __syncthreads();   // implicit vmcnt drain: buf[cur] ready, buf[cur^1] free
    if (kt + 1 < ntiles) {
      async_ld16(Kg + (size_t)((kt + 1) * 64 + srow) * HDIM, &Ks[cur ^ 1][0] + tid * 8);
      async_ld16(Vg + (kt + 1) * 64, &Vs[cur ^ 1][0] + tid * 8);
    }

    // S = Q K^T  (16 q-rows x 64 k per wave)
    f32x4 sa[4] = {};
    #pragma unroll
    for (int n = 0; n < 4; ++n) {
      const int row = n * 16 + li;
      #pragma unroll
      for (int ks = 0; ks < 2; ++ks) {
        const int c = ks * 4 + g;
        bf16x8 kf = *(const bf16x8*)(&Ks[cur][0] + row * 64 + ((c ^ (row & 7)) * 8));
        sa[n] = __builtin_amdgcn_mfma_f32_16x16x32_bf16(qf[ks], kf, sa[n], 0, 0, 0);
      }
    }

    // online softmax (wave-parallel, 16-lane groups)
    float pv[4][4];
    float mt[4];
    #pragma unroll
    for (int r = 0; r < 4; ++r) mt[r] = NEG_INF;
    #pragma unroll
    for (int n = 0; n < 4; ++n)
      #pragma unroll
      for (int r = 0; r < 4; ++r) {
        float s = sa[n][r] * 0.125f;
        int kg = kt * 64 + n * 16 + li;
        int qg = qrow0 + g * 4 + r;
        if (kg > qg) s = NEG_INF;
        pv[n][r] = s;
        mt[r] = fmaxf(mt[r], s);
      }
    #pragma unroll
    for (int r = 0; r < 4; ++r)
      #pragma unroll
      for (int m = 1; m < 16; m <<= 1) mt[r] = fmaxf(mt[r], __shfl_xor(mt[r], m, 64));

    float lt[4];
    #pragma unroll
    for (int r = 0; r < 4; ++r) {
      float mn = fmaxf(m_run[r], mt[r]);
      float al = __expf(m_run[r] - mn);
      m_run[r] = mn;
      float s = 0.f;
      #pragma unroll
      for (int n = 0; n < 4; ++n) {
        float p = __expf(pv[n][r] - mn);
        pv[n][r] = p;
        s += p;
      }
      lt[r] = s;
      l_run[r] *= al;
      #pragma unroll
      for (int n = 0; n < 4; ++n) po[n][r] *= al;
    }
    #pragma unroll
    for (int r = 0; r < 4; ++r) {
      #pragma unroll
      for (int m = 1; m < 16; m <<= 1) lt[r] += __shfl_xor(lt[r], m, 64);
      l_run[r] += lt[r];
    }

    // P -> per-wave LDS (bf16), stride 72; wave-private so no barrier needed
    #pragma unroll
    for (int n = 0; n < 4; ++n)
      #pragma unroll
      for (int r = 0; r < 4; ++r)
        Pl[wid][(g * 4 + r) * 72 + n * 16 + li] = f2bf(pv[n][r]);
    asm volatile("s_waitcnt lgkmcnt(0)" ::: "memory");

    // O += P V  (Vs holds V^T tile: row d, k contiguous, swizzled)
    #pragma unroll
    for (int ks = 0; ks < 2; ++ks) {
      bf16x8 pa = *(const bf16x8*)(Pl[wid] + li * 72 + ks * 32 + g * 8);
      #pragma unroll
      for (int n = 0; n < 4; ++n) {
        const int row = n * 16 + li;
        const int c = ks * 4 + g;
        bf16x8 vf = *(const bf16x8*)(&Vs[cur][0] + row * 64 + ((c ^ (row & 7)) * 8));
        po[n] = __builtin_amdgcn_mfma_f32_16x16x32_bf16(pa, vf, po[n], 0, 0, 0);
      }
    }
    cur ^= 1;
  }

  // epilogue: ctx [B*S, E] bf16
  #pragma unroll
  for (int n = 0; n < 4; ++n)
    #pragma unroll
    for (int r = 0; r < 4; ++r) {
      float o = po[n][r] / l_run[r];
      int row = b * SEQ + qb * 128 + wid * 16 + g * 4 + r;
      int col = h * HDIM + n * 16 + li;
      ctx[(size_t)row * EMBED + col] = f2bf(o);
    }
}

// ---------------- fused residual-add + LayerNorm ----------------
__global__ __launch_bounds__(256) void k_add_ln(
    const float* __restrict__ a, const float* __restrict__ bmat,
    const float* __restrict__ gam, const float* __restrict__ bet,
    float* __restrict__ outf, u16* __restrict__ outb) {
  const int row = blockIdx.x;
  const int t = threadIdx.x;
  __shared__ float red[8];
  float4 va = ((const float4*)(a + (size_t)row * EMBED))[t];
  float4 vb = ((const float4*)(bmat + (size_t)row * EMBED))[t];
  float s0 = va.x + vb.x, s1 = va.y + vb.y, s2 = va.z + vb.z, s3 = va.w + vb.w;
  float sum = s0 + s1 + s2 + s3;
  float sq = s0 * s0 + s1 * s1 + s2 * s2 + s3 * s3;
  #pragma unroll
  for (int m = 1; m < 64; m <<= 1) {
    sum += __shfl_xor(sum, m, 64);
    sq += __shfl_xor(sq, m, 64);
  }
  int wid = t >> 6;
  if ((t & 63) == 0) { red[wid] = sum; red[4 + wid] = sq; }
  __syncthreads();
  sum = red[0] + red[1] + red[2] + red[3];
  sq = red[4] + red[5] + red[6] + red[7];
  float mean = sum * (1.f / EMBED);
  float var = sq * (1.f / EMBED) - mean * mean;
  float rstd = rsqrtf(var + 1e-5f);
  float4 gv = ((const float4*)gam)[t], bev = ((const float4*)bet)[t];
  float y0 = (s0 - mean) * rstd * gv.x + bev.x;
  float y1 = (s1 - mean) * rstd * gv.y + bev.y;
  float y2 = (s2 - mean) * rstd * gv.z + bev.z;
  float y3 = (s3 - mean) * rstd * gv.w + bev.w;
  float4 o; o.x = y0; o.y = y1; o.z = y2; o.w = y3;
  ((float4*)(outf + (size_t)row * EMBED))[t] = o;
  if (outb) {
    ushort4 ob; ob.x = f2bf(y0); ob.y = f2bf(y1); ob.z = f2bf(y2); ob.w = f2bf(y3);
    ((ushort4*)(outb + (size_t)row * EMBED))[t] = ob;
  }
}

extern "C" void kernel_launch(void* const* d_in, const int* in_sizes, int n_in,
                              void* d_out, int out_size, void* d_ws, size_t ws_size,
                              hipStream_t stream) {
  const float* x      = (const float*)d_in[0];
  const float* w_qkv  = (const float*)d_in[1];
  const float* b_qkv  = (const float*)d_in[2];
  const float* w_out  = (const float*)d_in[3];
  const float* b_out  = (const float*)d_in[4];
  const float* w_up   = (const float*)d_in[5];
  const float* b_up   = (const float*)d_in[6];
  const float* w_down = (const float*)d_in[7];
  const float* b_down = (const float*)d_in[8];
  const float* g1  = (const float*)d_in[9];
  const float* be1 = (const float*)d_in[10];
  const float* g2  = (const float*)d_in[11];
  const float* be2 = (const float*)d_in[12];

  char* ws = (char*)d_ws;
  size_t off = 0;
  auto alloc = [&](size_t bytes) { void* p = ws + off; off += (bytes + 255) & ~(size_t)255; return p; };

  u16* xb     = (u16*)alloc((size_t)MTOT * EMBED * 2);
  u16* wqkvT  = (u16*)alloc((size_t)3 * EMBED * EMBED * 2);
  u16* woutT  = (u16*)alloc((size_t)EMBED * EMBED * 2);
  u16* wupT   = (u16*)alloc((size_t)FFN * EMBED * 2);
  u16* wdownT = (u16*)alloc((size_t)EMBED * FFN * 2);
  u16* qb     = (u16*)alloc((size_t)MTOT * EMBED * 2);
  u16* kb     = (u16*)alloc((size_t)MTOT * EMBED * 2);
  u16* vb     = (u16*)alloc((size_t)MTOT * EMBED * 2);
  u16* vtb    = (u16*)alloc((size_t)MTOT * EMBED * 2);
  u16* ctx    = (u16*)alloc((size_t)MTOT * EMBED * 2);
  float* attn_proj = (float*)alloc((size_t)MTOT * EMBED * 4);
  float* y_f32     = (float*)alloc((size_t)MTOT * EMBED * 4);
  u16* y_bf16      = (u16*)alloc((size_t)MTOT * EMBED * 2);
  u16* hmid        = (u16*)alloc((size_t)MTOT * FFN * 2);
  float* ffn_o     = (float*)alloc((size_t)MTOT * EMBED * 4);

  dim3 trb(32, 8);
  k_cvt<<<2048, 256, 0, stream>>>(x, xb, MTOT * EMBED / 4);
  k_tr<<<dim3(3 * EMBED / 32, EMBED / 32), trb, 0, stream>>>(w_qkv, wqkvT, EMBED, 3 * EMBED);
  k_tr<<<dim3(EMBED / 32, EMBED / 32), trb, 0, stream>>>(w_out, woutT, EMBED, EMBED);
  k_tr<<<dim3(FFN / 32, EMBED / 32), trb, 0, stream>>>(w_up, wupT, EMBED, FFN);
  k_tr<<<dim3(EMBED / 32, FFN / 32), trb, 0, stream>>>(w_down, wdownT, FFN, EMBED);

  k_gemm<128, 32, 2, false><<<dim3(3 * EMBED / 128, MTOT / 128), 256, 0, stream>>>(
      xb, wqkvT, b_qkv, qb, kb, vb, MTOT, 3 * EMBED, EMBED);

  k_vtr<<<dim3(SEQ / 64, BATCH * HEADS), 256, 0, stream>>>(vb, vtb);

  k_attn2<<<dim3(SEQ / 128, BATCH * HEADS), 512, 0, stream>>>(qb, kb, vtb, ctx);

  k_gemm<64, 64, 1, false><<<dim3(EMBED / 64, MTOT / 128), 256, 0, stream>>>(
      ctx, woutT, b_out, attn_proj, nullptr, nullptr, MTOT, EMBED, EMBED);

  k_add_ln<<<MTOT, 256, 0, stream>>>(x, attn_proj, g1, be1, y_f32, y_bf16);

  k_gemm<128, 32, 0, true><<<dim3(FFN / 128, MTOT / 128), 256, 0, stream>>>(
      y_bf16, wupT, b_up, hmid, nullptr, nullptr, MTOT, FFN, EMBED);

  k_gemm<64, 64, 1, false><<<dim3(EMBED / 64, MTOT / 128), 256, 0, stream>>>(
      hmid, wdownT, b_down, ffn_o, nullptr, nullptr, MTOT, EMBED, FFN);

  k_add_ln<<<MTOT, 256, 0, stream>>>(y_f32, ffn_o, g2, be2, (float*)d_out, nullptr);

  (void)in_sizes; (void)n_in; (void)out_size; (void)ws_size;
}

// Round 4
// 279.852 us; speedup vs baseline: 1.4769x; 1.1115x over previous
//
#include <hip/hip_runtime.h>
#include <hip/hip_bf16.h>

#define EMBED 1024
#define HEADS 16
#define HDIM 64
#define FFN 4096
#define SEQ 2048
#define BATCH 2
#define MTOT (BATCH*SEQ)
#define QSCALE 0.1803368801111137f   // 0.125 * log2(e)

typedef __attribute__((ext_vector_type(8))) short bf16x8;
typedef __attribute__((ext_vector_type(4))) float f32x4;
typedef __attribute__((ext_vector_type(16))) float f32x16;
typedef unsigned short u16;
typedef unsigned int u32;

__device__ __forceinline__ u16 f2bf(float f) {
  union { float f; unsigned u; } v; v.f = f;
  unsigned r = v.u + 0x7FFFu + ((v.u >> 16) & 1u);
  return (u16)(r >> 16);
}

__device__ __forceinline__ void async_ld16(const void* g, void* l) {
  __builtin_amdgcn_global_load_lds((const __attribute__((address_space(1))) void*)g,
                                   (__attribute__((address_space(3))) void*)l,
                                   16, 0, 0);
}

// ---------------- fp32 -> bf16 convert (vectorized) ----------------
__global__ __launch_bounds__(256) void k_cvt(const float* __restrict__ in,
                                             u16* __restrict__ out, int n4) {
  int i = blockIdx.x * 256 + threadIdx.x;
  int st = gridDim.x * 256;
  for (; i < n4; i += st) {
    float4 v = ((const float4*)in)[i];
    ushort4 o;
    o.x = f2bf(v.x); o.y = f2bf(v.y); o.z = f2bf(v.z); o.w = f2bf(v.w);
    ((ushort4*)out)[i] = o;
  }
}

// ---------------- transpose-convert: w[K,N] fp32 -> wT[N,K] bf16 ----------------
__global__ __launch_bounds__(256) void k_tr(const float* __restrict__ w,
                                            u16* __restrict__ wT, int K, int N) {
  __shared__ u16 tile[32][33];
  int n0 = blockIdx.x * 32, k0 = blockIdx.y * 32;
  int tx = threadIdx.x, ty = threadIdx.y;   // blockDim (32,8)
  #pragma unroll
  for (int i = 0; i < 4; ++i) {
    int k = k0 + ty + i * 8;
    tile[ty + i * 8][tx] = f2bf(w[(size_t)k * N + n0 + tx]);
  }
  __syncthreads();
  #pragma unroll
  for (int i = 0; i < 4; ++i) {
    int n = n0 + ty + i * 8;
    wT[(size_t)n * K + k0 + tx] = tile[tx][ty + i * 8];
  }
}

// ---------------- bf16 transpose: V [BH, S, 64] -> Vt [BH, 64, S] ----------------
__global__ __launch_bounds__(256) void k_vtr(const u16* __restrict__ V,
                                             u16* __restrict__ Vt) {
  __shared__ u16 t[64][72];   // [d][s]
  const int s0 = blockIdx.x * 64;
  const size_t ib = (size_t)blockIdx.y * (size_t)SEQ * HDIM;
  const size_t ob = (size_t)blockIdx.y * (size_t)HDIM * SEQ;
  const int tid = threadIdx.x;
  const int r = tid >> 2, c0 = (tid & 3) * 16;
  bf16x8 v0 = *(const bf16x8*)(V + ib + (size_t)(s0 + r) * HDIM + c0);
  bf16x8 v1 = *(const bf16x8*)(V + ib + (size_t)(s0 + r) * HDIM + c0 + 8);
  #pragma unroll
  for (int j = 0; j < 8; ++j) {
    t[c0 + j][r] = (u16)v0[j];
    t[c0 + 8 + j][r] = (u16)v1[j];
  }
  __syncthreads();
  const int d = tid >> 2, sc = (tid & 3) * 16;
  bf16x8 o0, o1;
  #pragma unroll
  for (int j = 0; j < 8; ++j) { o0[j] = t[d][sc + j]; o1[j] = t[d][sc + 8 + j]; }
  *(bf16x8*)(Vt + ob + (size_t)d * SEQ + s0 + sc) = o0;
  *(bf16x8*)(Vt + ob + (size_t)d * SEQ + s0 + sc + 8) = o1;
}

// ---------------- MFMA GEMM: C[M,N] = A[M,K] @ BT[N,K]^T + bias ----------------
template <int BN, int BK, int OMODE, bool RELU>
__global__ __launch_bounds__(256) void k_gemm(
    const u16* __restrict__ A, const u16* __restrict__ BT,
    const float* __restrict__ bias,
    void* __restrict__ out0, void* __restrict__ out1, void* __restrict__ out2,
    int M, int N, int K) {
  constexpr int NR = BN / 32;
  constexpr int KS = BK / 32;
  constexpr int TPR = BK / 8;
  constexpr int RPI = 256 / TPR;
  constexpr int CM = TPR - 1;

  __shared__ u16 As[2][128 * BK];
  __shared__ u16 Bs[2][BN * BK];
  const int tid = threadIdx.x;
  const int lane = tid & 63, g = lane >> 4, li = lane & 15;
  const int wid = tid >> 6, wm = wid >> 1, wn = wid & 1;
  const int m0 = blockIdx.y * 128, n0 = blockIdx.x * BN;

  f32x4 acc[4][NR] = {};

  const u16* Ablk = A + (size_t)m0 * K;
  const u16* Bblk = BT + (size_t)n0 * K;
  const int srow = tid / TPR;
  const int scol = ((tid % TPR) ^ (srow & CM)) * 8;

  auto stage = [&](int buf, int kt) {
    #pragma unroll
    for (int r = 0; r < 128; r += RPI)
      async_ld16(Ablk + (size_t)(srow + r) * K + kt + scol, &As[buf][(srow + r) * BK] + (tid % TPR) * 8);
    #pragma unroll
    for (int r = 0; r < BN; r += RPI)
      async_ld16(Bblk + (size_t)(srow + r) * K + kt + scol, &Bs[buf][(srow + r) * BK] + (tid % TPR) * 8);
  };

  stage(0, 0);
  int cur = 0;
  for (int kt = 0; kt < K; kt += BK) {
    __syncthreads();
    if (kt + BK < K) stage(cur ^ 1, kt + BK);

    bf16x8 af[4][KS], bfr[NR][KS];
    #pragma unroll
    for (int i = 0; i < 4; ++i) {
      const int row = wm * 64 + i * 16 + li;
      #pragma unroll
      for (int ks = 0; ks < KS; ++ks) {
        const int c = ks * 4 + g;
        af[i][ks] = *(const bf16x8*)(&As[cur][row * BK] + ((c ^ (row & CM)) & CM) * 8);
      }
    }
    #pragma unroll
    for (int j = 0; j < NR; ++j) {
      const int row = wn * (BN / 2) + j * 16 + li;
      #pragma unroll
      for (int ks = 0; ks < KS; ++ks) {
        const int c = ks * 4 + g;
        bfr[j][ks] = *(const bf16x8*)(&Bs[cur][row * BK] + ((c ^ (row & CM)) & CM) * 8);
      }
    }
    #pragma unroll
    for (int ks = 0; ks < KS; ++ks)
      #pragma unroll
      for (int i = 0; i < 4; ++i)
        #pragma unroll
        for (int j = 0; j < NR; ++j)
          acc[i][j] = __builtin_amdgcn_mfma_f32_16x16x32_bf16(af[i][ks], bfr[j][ks], acc[i][j], 0, 0, 0);
    cur ^= 1;
  }

  float bcol[NR];
  #pragma unroll
  for (int j = 0; j < NR; ++j) bcol[j] = bias[n0 + wn * (BN / 2) + j * 16 + li];

  #pragma unroll
  for (int i = 0; i < 4; ++i) {
    #pragma unroll
    for (int j = 0; j < NR; ++j) {
      #pragma unroll
      for (int r = 0; r < 4; ++r) {
        int row = m0 + wm * 64 + i * 16 + g * 4 + r;
        int col = n0 + wn * (BN / 2) + j * 16 + li;
        float v = acc[i][j][r] + bcol[j];
        if (RELU) v = fmaxf(v, 0.f);
        if (OMODE == 0) {
          ((u16*)out0)[(size_t)row * N + col] = f2bf(v);
        } else if (OMODE == 1) {
          ((float*)out0)[(size_t)row * N + col] = v;
        } else {
          int which = col >> 10, hh = (col >> 6) & 15, d = col & 63;
          int bb = row >> 11, ss = row & 2047;
          if (which == 0) v *= QSCALE;   // pre-scale Q for exp2-domain softmax
          u16* dst = which == 0 ? (u16*)out0 : (which == 1 ? (u16*)out1 : (u16*)out2);
          dst[((size_t)((bb * 16 + hh) * 2048 + ss)) * 64 + d] = f2bf(v);
        }
      }
    }
  }
}

// ---------------- Flash attention, swapped-QK^T 32x32 structure ----------------
// grid (BH=32, 16); 4 waves x 32 q-rows = 128 rows/block. S^T = K.Q^T (lane owns
// q-row: col=lane&31), in-register softmax in exp2 domain (Q pre-scaled),
// P kept in registers (cvt_pk + shfl_xor(32)), O^T = V^T.P^T.
__global__ __launch_bounds__(256) void k_attn3(
    const u16* __restrict__ Q, const u16* __restrict__ K,
    const u16* __restrict__ Vt, u16* __restrict__ ctx) {
  const int bh = blockIdx.x;
  const int z  = blockIdx.y;
  const int qb = (z < 8) ? (2 * z) : (31 - 2 * z);   // balanced pairing
  const int b = bh >> 4, h = bh & 15;
  const int tid = threadIdx.x;
  const int wid = tid >> 6, lane = tid & 63;
  const int ql = lane & 31, hl = lane >> 5;

  __shared__ u16 Ks[2][64 * 64];
  __shared__ u16 Vs[2][64 * 64];

  const size_t kbase = (size_t)bh * SEQ * HDIM;   // Q,K: [BH,S,D]
  const size_t vbase = (size_t)bh * HDIM * SEQ;   // Vt:  [BH,D,S]
  const int wq0 = qb * 128 + wid * 32;
  const int qg = wq0 + ql;

  bf16x8 qf[4];   // B-frag of K.Q^T: lane holds q-col=ql, d contiguous
  #pragma unroll
  for (int d4 = 0; d4 < 4; ++d4)
    qf[d4] = *(const bf16x8*)(Q + kbase + (size_t)qg * HDIM + d4 * 16 + hl * 8);

  f32x16 o0 = {}, o1 = {};       // O^T: col q=ql, rows d=(r&3)+8*(r>>2)+4*hl (+32)
  float m_run = -1e30f, l_run = 0.f;

  const int srow = tid >> 3;
  const int scol = ((tid & 7) ^ (srow & 7)) * 8;

  auto stage = [&](int buf, int t2) {
    const u16* kg = K + kbase + (size_t)(t2 * 64 + srow) * HDIM + scol;
    async_ld16(kg, &Ks[buf][0] + tid * 8);
    async_ld16(kg + (size_t)32 * HDIM, &Ks[buf][0] + 2048 + tid * 8);
    const u16* vg = Vt + vbase + (size_t)srow * SEQ + t2 * 64 + scol;
    async_ld16(vg, &Vs[buf][0] + tid * 8);
    async_ld16(vg + (size_t)32 * SEQ, &Vs[buf][0] + 2048 + tid * 8);
  };

  const int ntiles = 2 * qb + 2;
  stage(0, 0);
  int cur = 0;

  for (int kt = 0; kt < ntiles; ++kt) {
    __syncthreads();                       // drains prefetch of buf[cur]
    if (kt + 1 < ntiles) stage(cur ^ 1, kt + 1);

    if (kt * 64 <= wq0 + 31) {             // wave-uniform: any unmasked k?
      const bool kh1 = (kt * 64 + 32 <= wq0 + 31);
      const bool domask = (kt * 64 + (kh1 ? 63 : 31) > wq0);

      f32x16 S0 = {}, S1 = {};
      #pragma unroll
      for (int d4 = 0; d4 < 4; ++d4) {
        bf16x8 kf = *(const bf16x8*)(&Ks[cur][0] + ql * 64 + (((2 * d4 + hl) ^ (ql & 7)) * 8));
        S0 = __builtin_amdgcn_mfma_f32_32x32x16_bf16(kf, qf[d4], S0, 0, 0, 0);
      }
      if (kh1) {
        #pragma unroll
        for (int d4 = 0; d4 < 4; ++d4) {
          const int row = 32 + ql;
          bf16x8 kf = *(const bf16x8*)(&Ks[cur][0] + row * 64 + (((2 * d4 + hl) ^ (row & 7)) * 8));
          S1 = __builtin_amdgcn_mfma_f32_32x32x16_bf16(kf, qf[d4], S1, 0, 0, 0);
        }
      }

      if (domask) {
        const int qrel = qg - kt * 64 - 4 * hl;
        #pragma unroll
        for (int r = 0; r < 16; ++r) {
          const int kc = (r & 3) + 8 * (r >> 2);
          S0[r] = (kc <= qrel) ? S0[r] : -3.0e38f;
        }
        if (kh1) {
          #pragma unroll
          for (int r = 0; r < 16; ++r) {
            const int kc = 32 + (r & 3) + 8 * (r >> 2);
            S1[r] = (kc <= qrel) ? S1[r] : -3.0e38f;
          }
        }
      }

      // in-register row max / sum (partner lane ql^32 holds same q, other k)
      float mt = -3.0e38f;
      #pragma unroll
      for (int r = 0; r < 16; ++r) mt = fmaxf(mt, S0[r]);
      if (kh1) {
        #pragma unroll
        for (int r = 0; r < 16; ++r) mt = fmaxf(mt, S1[r]);
      }
      mt = fmaxf(mt, __shfl_xor(mt, 32, 64));
      const float mn = fmaxf(m_run, mt);
      const float alpha = exp2f(m_run - mn);
      float sum = 0.f;
      #pragma unroll
      for (int r = 0; r < 16; ++r) { S0[r] = exp2f(S0[r] - mn); sum += S0[r]; }
      if (kh1) {
        #pragma unroll
        for (int r = 0; r < 16; ++r) { S1[r] = exp2f(S1[r] - mn); sum += S1[r]; }
      }
      sum += __shfl_xor(sum, 32, 64);
      l_run = l_run * alpha + sum;
      m_run = mn;
      o0 *= alpha;
      o1 *= alpha;

      // P (f32) -> packed bf16 dwords; quad (c,m) = k [32c+8m+4hl, +4)
      u32 pk[2][8], sw[2][8];
      #pragma unroll
      for (int m = 0; m < 4; ++m) {
        asm("v_cvt_pk_bf16_f32 %0, %1, %2" : "=v"(pk[0][2*m])   : "v"(S0[4*m+0]), "v"(S0[4*m+1]));
        asm("v_cvt_pk_bf16_f32 %0, %1, %2" : "=v"(pk[0][2*m+1]) : "v"(S0[4*m+2]), "v"(S0[4*m+3]));
      }
      #pragma unroll
      for (int i = 0; i < 8; ++i) sw[0][i] = __shfl_xor(pk[0][i], 32, 64);
      if (kh1) {
        #pragma unroll
        for (int m = 0; m < 4; ++m) {
          asm("v_cvt_pk_bf16_f32 %0, %1, %2" : "=v"(pk[1][2*m])   : "v"(S1[4*m+0]), "v"(S1[4*m+1]));
          asm("v_cvt_pk_bf16_f32 %0, %1, %2" : "=v"(pk[1][2*m+1]) : "v"(S1[4*m+2]), "v"(S1[4*m+3]));
        }
        #pragma unroll
        for (int i = 0; i < 8; ++i) sw[1][i] = __shfl_xor(pk[1][i], 32, 64);
      }

      // O^T += V^T . P^T : B-frag(t): lane k = 16t+8hl+j
      #pragma unroll
      for (int t = 0; t < 4; ++t) {
        if (t < 2 || kh1) {
          const int c = t >> 1, m0 = 2 * (t & 1), m1 = m0 + 1;
          union { u32 u[4]; bf16x8 v; } pf;
          pf.u[0] = hl ? sw[c][2*m1]   : pk[c][2*m0];
          pf.u[1] = hl ? sw[c][2*m1+1] : pk[c][2*m0+1];
          pf.u[2] = hl ? pk[c][2*m1]   : sw[c][2*m0];
          pf.u[3] = hl ? pk[c][2*m1+1] : sw[c][2*m0+1];
          {
            bf16x8 vf = *(const bf16x8*)(&Vs[cur][0] + ql * 64 + (((2 * t + hl) ^ (ql & 7)) * 8));
            o0 = __builtin_amdgcn_mfma_f32_32x32x16_bf16(vf, pf.v, o0, 0, 0, 0);
          }
          {
            const int row = 32 + ql;
            bf16x8 vf = *(const bf16x8*)(&Vs[cur][0] + row * 64 + (((2 * t + hl) ^ (row & 7)) * 8));
            o1 = __builtin_amdgcn_mfma_f32_32x32x16_bf16(vf, pf.v, o1, 0, 0, 0);
          }
        }
      }
    }
    cur ^= 1;
  }

  const float inv = 1.f / l_run;
  u16* outp = ctx + (size_t)(b * SEQ + qg) * EMBED + h * HDIM + 4 * hl;
  #pragma unroll
  for (int m = 0; m < 4; ++m) {
    ushort4 s0v, s1v;
    s0v.x = f2bf(o0[4*m+0] * inv); s0v.y = f2bf(o0[4*m+1] * inv);
    s0v.z = f2bf(o0[4*m+2] * inv); s0v.w = f2bf(o0[4*m+3] * inv);
    *(ushort4*)(outp + 8 * m) = s0v;
    s1v.x = f2bf(o1[4*m+0] * inv); s1v.y = f2bf(o1[4*m+1] * inv);
    s1v.z = f2bf(o1[4*m+2] * inv); s1v.w = f2bf(o1[4*m+3] * inv);
    *(ushort4*)(outp + 32 + 8 * m) = s1v;
  }
}

// ---------------- fused residual-add + LayerNorm ----------------
__global__ __launch_bounds__(256) void k_add_ln(
    const float* __restrict__ a, const float* __restrict__ bmat,
    const float* __restrict__ gam, const float* __restrict__ bet,
    float* __restrict__ outf, u16* __restrict__ outb) {
  const int row = blockIdx.x;
  const int t = threadIdx.x;
  __shared__ float red[8];
  float4 va = ((const float4*)(a + (size_t)row * EMBED))[t];
  float4 vb = ((const float4*)(bmat + (size_t)row * EMBED))[t];
  float s0 = va.x + vb.x, s1 = va.y + vb.y, s2 = va.z + vb.z, s3 = va.w + vb.w;
  float sum = s0 + s1 + s2 + s3;
  float sq = s0 * s0 + s1 * s1 + s2 * s2 + s3 * s3;
  #pragma unroll
  for (int m = 1; m < 64; m <<= 1) {
    sum += __shfl_xor(sum, m, 64);
    sq += __shfl_xor(sq, m, 64);
  }
  int wid = t >> 6;
  if ((t & 63) == 0) { red[wid] = sum; red[4 + wid] = sq; }
  __syncthreads();
  sum = red[0] + red[1] + red[2] + red[3];
  sq = red[4] + red[5] + red[6] + red[7];
  float mean = sum * (1.f / EMBED);
  float var = sq * (1.f / EMBED) - mean * mean;
  float rstd = rsqrtf(var + 1e-5f);
  float4 gv = ((const float4*)gam)[t], bev = ((const float4*)bet)[t];
  float y0 = (s0 - mean) * rstd * gv.x + bev.x;
  float y1 = (s1 - mean) * rstd * gv.y + bev.y;
  float y2 = (s2 - mean) * rstd * gv.z + bev.z;
  float y3 = (s3 - mean) * rstd * gv.w + bev.w;
  float4 o; o.x = y0; o.y = y1; o.z = y2; o.w = y3;
  ((float4*)(outf + (size_t)row * EMBED))[t] = o;
  if (outb) {
    ushort4 ob; ob.x = f2bf(y0); ob.y = f2bf(y1); ob.z = f2bf(y2); ob.w = f2bf(y3);
    ((ushort4*)(outb + (size_t)row * EMBED))[t] = ob;
  }
}

extern "C" void kernel_launch(void* const* d_in, const int* in_sizes, int n_in,
                              void* d_out, int out_size, void* d_ws, size_t ws_size,
                              hipStream_t stream) {
  const float* x      = (const float*)d_in[0];
  const float* w_qkv  = (const float*)d_in[1];
  const float* b_qkv  = (const float*)d_in[2];
  const float* w_out  = (const float*)d_in[3];
  const float* b_out  = (const float*)d_in[4];
  const float* w_up   = (const float*)d_in[5];
  const float* b_up   = (const float*)d_in[6];
  const float* w_down = (const float*)d_in[7];
  const float* b_down = (const float*)d_in[8];
  const float* g1  = (const float*)d_in[9];
  const float* be1 = (const float*)d_in[10];
  const float* g2  = (const float*)d_in[11];
  const float* be2 = (const float*)d_in[12];

  char* ws = (char*)d_ws;
  size_t off = 0;
  auto alloc = [&](size_t bytes) { void* p = ws + off; off += (bytes + 255) & ~(size_t)255; return p; };

  u16* xb     = (u16*)alloc((size_t)MTOT * EMBED * 2);
  u16* wqkvT  = (u16*)alloc((size_t)3 * EMBED * EMBED * 2);
  u16* woutT  = (u16*)alloc((size_t)EMBED * EMBED * 2);
  u16* wupT   = (u16*)alloc((size_t)FFN * EMBED * 2);
  u16* wdownT = (u16*)alloc((size_t)EMBED * FFN * 2);
  u16* qb     = (u16*)alloc((size_t)MTOT * EMBED * 2);
  u16* kb     = (u16*)alloc((size_t)MTOT * EMBED * 2);
  u16* vb     = (u16*)alloc((size_t)MTOT * EMBED * 2);
  u16* vtb    = (u16*)alloc((size_t)MTOT * EMBED * 2);
  u16* ctx    = (u16*)alloc((size_t)MTOT * EMBED * 2);
  float* attn_proj = (float*)alloc((size_t)MTOT * EMBED * 4);
  float* y_f32     = (float*)alloc((size_t)MTOT * EMBED * 4);
  u16* y_bf16      = (u16*)alloc((size_t)MTOT * EMBED * 2);
  u16* hmid        = (u16*)alloc((size_t)MTOT * FFN * 2);
  float* ffn_o     = (float*)alloc((size_t)MTOT * EMBED * 4);

  dim3 trb(32, 8);
  k_cvt<<<2048, 256, 0, stream>>>(x, xb, MTOT * EMBED / 4);
  k_tr<<<dim3(3 * EMBED / 32, EMBED / 32), trb, 0, stream>>>(w_qkv, wqkvT, EMBED, 3 * EMBED);
  k_tr<<<dim3(EMBED / 32, EMBED / 32), trb, 0, stream>>>(w_out, woutT, EMBED, EMBED);
  k_tr<<<dim3(FFN / 32, EMBED / 32), trb, 0, stream>>>(w_up, wupT, EMBED, FFN);
  k_tr<<<dim3(EMBED / 32, FFN / 32), trb, 0, stream>>>(w_down, wdownT, FFN, EMBED);

  k_gemm<128, 32, 2, false><<<dim3(3 * EMBED / 128, MTOT / 128), 256, 0, stream>>>(
      xb, wqkvT, b_qkv, qb, kb, vb, MTOT, 3 * EMBED, EMBED);

  k_vtr<<<dim3(SEQ / 64, BATCH * HEADS), 256, 0, stream>>>(vb, vtb);

  k_attn3<<<dim3(BATCH * HEADS, 16), 256, 0, stream>>>(qb, kb, vtb, ctx);

  k_gemm<64, 64, 1, false><<<dim3(EMBED / 64, MTOT / 128), 256, 0, stream>>>(
      ctx, woutT, b_out, attn_proj, nullptr, nullptr, MTOT, EMBED, EMBED);

  k_add_ln<<<MTOT, 256, 0, stream>>>(x, attn_proj, g1, be1, y_f32, y_bf16);

  k_gemm<128, 32, 0, true><<<dim3(FFN / 128, MTOT / 128), 256, 0, stream>>>(
      y_bf16, wupT, b_up, hmid, nullptr, nullptr, MTOT, FFN, EMBED);

  k_gemm<64, 64, 1, false><<<dim3(EMBED / 64, MTOT / 128), 256, 0, stream>>>(
      hmid, wdownT, b_down, ffn_o, nullptr, nullptr, MTOT, EMBED, FFN);

  k_add_ln<<<MTOT, 256, 0, stream>>>(y_f32, ffn_o, g2, be2, (float*)d_out, nullptr);

  (void)in_sizes; (void)n_in; (void)out_size; (void)ws_size;
}